// Round 3
// baseline (277.231 us; speedup 1.0000x reference)
//
#include <hip/hip_runtime.h>

typedef unsigned short ushort_t;
typedef unsigned int uint_t;
typedef __bf16 bf16x8 __attribute__((ext_vector_type(8)));
typedef float f32x4 __attribute__((ext_vector_type(4)));

__device__ __forceinline__ ushort_t f2bf(float f) {
  union { float f; unsigned u; } x;
  x.f = f;
  unsigned r = x.u + 0x7fffu + ((x.u >> 16) & 1u);
  return (ushort_t)(r >> 16);
}
__device__ __forceinline__ float bf2f(ushort_t u) {
  union { unsigned u; float f; } x;
  x.u = (unsigned)u << 16;
  return x.f;
}
#if __has_builtin(__builtin_amdgcn_cvt_pk_bf16_f32)
__device__ __forceinline__ uint_t pack2bf(float a, float b) {
  auto v = __builtin_amdgcn_cvt_pk_bf16_f32(a, b);
  uint_t u; __builtin_memcpy(&u, &v, 4); return u;
}
#else
__device__ __forceinline__ uint_t pack2bf(float a, float b) {
  return (uint_t)f2bf(a) | ((uint_t)f2bf(b) << 16);
}
#endif

// async global->LDS, 16 B/lane; LDS dest = wave-uniform base + lane*16.
__device__ __forceinline__ void async_copy16(const ushort_t* g, ushort_t* l) {
  __builtin_amdgcn_global_load_lds(
      (const __attribute__((address_space(1))) unsigned int*)g,
      (__attribute__((address_space(3))) unsigned int*)l, 16, 0, 0);
}

// ---------------------------------------------------------------------------
// Fused prep: [0,3072) convert x fp32->bf16; [3072,3504) transpose w_qkv;
// [3504,3648) transpose w_out.  Grid: (3648), 256 threads.
// ---------------------------------------------------------------------------
__global__ __launch_bounds__(256) void prep_kernel(const float* __restrict__ x,
                                                   const float* __restrict__ w_qkv,
                                                   const float* __restrict__ w_out,
                                                   ushort_t* __restrict__ x_bf,
                                                   ushort_t* __restrict__ wqkv_t,
                                                   ushort_t* __restrict__ wout_t) {
  const int bx = blockIdx.x;
  if (bx < 3072) {  // convert x: 8 elems/thread
    const int i = (bx * 256 + threadIdx.x) * 8;
    float4 a = *(const float4*)(x + i);
    float4 b = *(const float4*)(x + i + 4);
    uint_t t[4];
    t[0] = pack2bf(a.x, a.y); t[1] = pack2bf(a.z, a.w);
    t[2] = pack2bf(b.x, b.y); t[3] = pack2bf(b.z, b.w);
    *(uint4*)(x_bf + i) = *(const uint4*)t;
    return;
  }
  // weight transpose: out[n][k] = bf16(in[k][n]), 64x64 tiles
  const float* in; ushort_t* outp; int K, N, n0, k0;
  if (bx < 3504) {
    int t = bx - 3072;                       // 36 x 12
    in = w_qkv; outp = wqkv_t; K = 768; N = 2304;
    n0 = (t % 36) * 64; k0 = (t / 36) * 64;
  } else {
    int t = bx - 3504;                       // 12 x 12
    in = w_out; outp = wout_t; K = 768; N = 768;
    n0 = (t % 12) * 64; k0 = (t / 12) * 64;
  }
  __shared__ ushort_t s[64][72];
  const int r = threadIdx.x >> 2;
  const int c = (threadIdx.x & 3) * 16;
  const float* src = in + (size_t)(k0 + r) * N + n0 + c;
  float buf[16];
#pragma unroll
  for (int i = 0; i < 16; i += 4) *(float4*)&buf[i] = *(const float4*)(src + i);
  ushort_t t16[16];
#pragma unroll
  for (int i = 0; i < 16; ++i) t16[i] = f2bf(buf[i]);
  *(uint4*)&s[r][c] = *(const uint4*)&t16[0];
  *(uint4*)&s[r][c + 8] = *(const uint4*)&t16[8];
  __syncthreads();
  ushort_t tmp[16];
#pragma unroll
  for (int i = 0; i < 16; ++i) tmp[i] = s[c + i][r];
  ushort_t* dst = outp + (size_t)(n0 + r) * K + k0 + c;
  *(uint4*)&dst[0] = *(const uint4*)&tmp[0];
  *(uint4*)&dst[8] = *(const uint4*)&tmp[8];
}

// ---------------------------------------------------------------------------
// Per-head V transpose: v_t[bh][d][s] = v[bh][s][d].  Grid: (64, 24).
// ---------------------------------------------------------------------------
__global__ __launch_bounds__(256) void transpose_v(const ushort_t* __restrict__ v,
                                                   ushort_t* __restrict__ v_t) {
  __shared__ ushort_t s[64][72];
  const int s0 = blockIdx.x * 64;
  const int bh = blockIdx.y;
  const ushort_t* src = v + ((size_t)bh * 4096 + s0) * 64;
  ushort_t* dst = v_t + (size_t)bh * 64 * 4096 + s0;
  const int r = threadIdx.x >> 2;
  const int c = (threadIdx.x & 3) * 16;
  *(uint4*)&s[r][c] = *(const uint4*)(src + (size_t)r * 64 + c);
  *(uint4*)&s[r][c + 8] = *(const uint4*)(src + (size_t)r * 64 + c + 8);
  __syncthreads();
  ushort_t tmp[16];
#pragma unroll
  for (int i = 0; i < 16; ++i) tmp[i] = s[c + i][r];
  *(uint4*)&dst[(size_t)r * 4096 + c] = *(const uint4*)&tmp[0];
  *(uint4*)&dst[(size_t)r * 4096 + c + 8] = *(const uint4*)&tmp[8];
}

// ---------------------------------------------------------------------------
// GEMM1 (m97-style): qkv = x_bf @ w_qkv.  128x128 tile, BK=32,
// global_load_lds staging.  Q pre-scaled by SCL.  Grid: (1152), 256 threads.
// ---------------------------------------------------------------------------
__global__ __launch_bounds__(256) void gemm128_qkv(const ushort_t* __restrict__ A,
                                                   const ushort_t* __restrict__ Bt,
                                                   ushort_t* __restrict__ qkv) {
  constexpr int K = 768;
  constexpr float SCL = 0.1803368801111137f;  // (1/sqrt(64)) * log2(e)
  __shared__ ushort_t sA[128 * 32];
  __shared__ ushort_t sB[128 * 32];
  const int bid = blockIdx.x;
  const int g = bid / 144, rr = bid - g * 144;
  const int mi = g * 8 + (rr & 7), ni = rr >> 3;   // mi 0..63, ni 0..17
  const int tid = threadIdx.x;
  const int lane = tid & 63, w = tid >> 6;
  const int wm = w >> 1, wn = w & 1;
  const int col = lane & 15, quad = lane >> 4;
  const int m0 = mi * 128, n0 = ni * 128;
  const int row = tid >> 2;
  const int kc = (tid & 3) * 8;
  f32x4 acc[4][4] = {};
  const ushort_t* aptr = A + (size_t)(m0 + row) * K + kc;
  const ushort_t* bptr = Bt + (size_t)(n0 + row) * K + kc;
  ushort_t* lA = sA + w * 512;
  ushort_t* lB = sB + w * 512;
  for (int k0 = 0; k0 < K; k0 += 32) {
    async_copy16(aptr + k0, lA);
    async_copy16(aptr + (size_t)64 * K + k0, lA + 2048);
    async_copy16(bptr + k0, lB);
    async_copy16(bptr + (size_t)64 * K + k0, lB + 2048);
    __syncthreads();
    bf16x8 af[4], bfr[4];
#pragma unroll
    for (int mt = 0; mt < 4; ++mt)
      af[mt] = *(const bf16x8*)&sA[(wm * 64 + mt * 16 + col) * 32 + quad * 8];
#pragma unroll
    for (int nt = 0; nt < 4; ++nt)
      bfr[nt] = *(const bf16x8*)&sB[(wn * 64 + nt * 16 + col) * 32 + quad * 8];
#pragma unroll
    for (int mt = 0; mt < 4; ++mt)
#pragma unroll
      for (int nt = 0; nt < 4; ++nt)
        acc[mt][nt] = __builtin_amdgcn_mfma_f32_16x16x32_bf16(af[mt], bfr[nt],
                                                              acc[mt][nt], 0, 0, 0);
    __syncthreads();
  }
  const int which = ni / 6;                     // 0=Q 1=K 2=V (block-uniform)
  const float qs = (which == 0) ? SCL : 1.0f;
#pragma unroll
  for (int mt = 0; mt < 4; ++mt)
#pragma unroll
    for (int nt = 0; nt < 4; ++nt)
#pragma unroll
      for (int r = 0; r < 4; ++r) {
        int m = m0 + wm * 64 + mt * 16 + quad * 4 + r;
        int n = n0 + wn * 64 + nt * 16 + col;
        int rem = n - which * 768;
        int h = rem >> 6, d = rem & 63;
        int b = m >> 12, s = m & 4095;
        qkv[(((size_t)(which * 24 + b * 12 + h) * 4096 + s) << 6) + d] =
            f2bf(acc[mt][nt][r] * qs);
      }
}

// ---------------------------------------------------------------------------
// GEMM2 (m97-style): out = ctx @ w_out, fp32 out.  Grid: (64, 6).
// ---------------------------------------------------------------------------
__global__ __launch_bounds__(256) void gemm128_out(const ushort_t* __restrict__ A,
                                                   const ushort_t* __restrict__ Bt,
                                                   float* __restrict__ out) {
  constexpr int K = 768;
  __shared__ ushort_t sA[128 * 32];
  __shared__ ushort_t sB[128 * 32];
  const int tid = threadIdx.x;
  const int lane = tid & 63, w = tid >> 6;
  const int wm = w >> 1, wn = w & 1;
  const int col = lane & 15, quad = lane >> 4;
  const int m0 = blockIdx.x * 128, n0 = blockIdx.y * 128;
  const int row = tid >> 2;
  const int kc = (tid & 3) * 8;
  f32x4 acc[4][4] = {};
  const ushort_t* aptr = A + (size_t)(m0 + row) * K + kc;
  const ushort_t* bptr = Bt + (size_t)(n0 + row) * K + kc;
  ushort_t* lA = sA + w * 512;
  ushort_t* lB = sB + w * 512;
  for (int k0 = 0; k0 < K; k0 += 32) {
    async_copy16(aptr + k0, lA);
    async_copy16(aptr + (size_t)64 * K + k0, lA + 2048);
    async_copy16(bptr + k0, lB);
    async_copy16(bptr + (size_t)64 * K + k0, lB + 2048);
    __syncthreads();
    bf16x8 af[4], bfr[4];
#pragma unroll
    for (int mt = 0; mt < 4; ++mt)
      af[mt] = *(const bf16x8*)&sA[(wm * 64 + mt * 16 + col) * 32 + quad * 8];
#pragma unroll
    for (int nt = 0; nt < 4; ++nt)
      bfr[nt] = *(const bf16x8*)&sB[(wn * 64 + nt * 16 + col) * 32 + quad * 8];
#pragma unroll
    for (int mt = 0; mt < 4; ++mt)
#pragma unroll
      for (int nt = 0; nt < 4; ++nt)
        acc[mt][nt] = __builtin_amdgcn_mfma_f32_16x16x32_bf16(af[mt], bfr[nt],
                                                              acc[mt][nt], 0, 0, 0);
    __syncthreads();
  }
#pragma unroll
  for (int mt = 0; mt < 4; ++mt)
#pragma unroll
    for (int nt = 0; nt < 4; ++nt)
#pragma unroll
      for (int r = 0; r < 4; ++r) {
        int m = m0 + wm * 64 + mt * 16 + quad * 4 + r;
        int n = n0 + wn * 64 + nt * 16 + col;
        out[(size_t)m * 768 + n] = acc[mt][nt][r];
      }
}

// ---------------------------------------------------------------------------
// Flash attention, causal, S^T formulation, Q-tile 128, UNIFORM SPLIT-K.
// Round-3 changes (theory: VALU/LDS-bound, MfmaUtil 20 / VALUBusy 57 /
// BANK_CONFLICT 1.1e7):
//  (a) fragment-linear LDS for K/V and the P^T scratch: every ds_read/write
//      is base + lane*16 (conflict-free); global source addresses are
//      pre-swizzled to the fragment mapping instead (guide §5 pattern).
//      Old [64][72] layout had (col+quad)&7 bank groups -> 8-way conflicts
//      on ALL fragment b128 reads.
//  (b) row-sum via ones-row MFMA into l_acc (f32x4, per-col like m_i),
//      replacing 15 adds + 2 serial shuffle-adds per strip.
// LDS 24 KB -> 6 blocks/CU.  launch_bounds(256,4): do NOT raise (r1: ,5
// capped VGPR at 48 -> spills).
// ---------------------------------------------------------------------------
__global__ __launch_bounds__(256, 4) void flash_kernel(const ushort_t* __restrict__ qkv,
                                                       const ushort_t* __restrict__ v_t,
                                                       ushort_t* __restrict__ ctx,
                                                       ushort_t* __restrict__ op0,
                                                       ushort_t* __restrict__ op1,
                                                       float* __restrict__ m_part,
                                                       float* __restrict__ l_part) {
  constexpr int S = 4096;
  constexpr int HD = 64;
  const int bh = blockIdx.y;
  const int b = bh / 12, h = bh - b * 12;

  // blockIdx.x -> (qt, chunk c), heavy qt first (bx=0 -> qt=31,c=0).
  int rem = blockIdx.x, qt = 31, C;
  for (;;) {
    C = (qt + 6) / 6;
    if (rem < C) break;
    rem -= C; --qt;
  }
  const int c = rem;
  const int T = 2 * qt + 2;                 // total KV tiles for this qt
  const bool direct = (C == 1);
  const int jstart = (c * T) / C;
  const int jend = ((c + 1) * T) / C - 1;   // inclusive
  int sb = 0;                               // partial-slot base for this qt
  for (int q = 6; q < qt; ++q) sb += (q + 6) / 6;
  const int slot = bh * 96 + sb + c;

  const ushort_t* Qp = qkv + (size_t)bh * S * HD;
  const ushort_t* Kp = qkv + (size_t)(24 + bh) * S * HD;
  const ushort_t* Vt = v_t + (size_t)bh * HD * S;

  // Fragment-linear LDS: 8 blocks x (64 lanes x 16B) each for K and V.
  //   K block fb = half*4 + nt, slot l: K[nt*16 + (l&15)][half*32 + (l>>4)*8 ..+8]
  //   V block fb = half*4 + dt, slot l: V^T[dt*16 + (l&15)][kv half*32 + (l>>4)*8]
  __shared__ __align__(16) ushort_t sK[4096];
  __shared__ __align__(16) ushort_t sV[4096];
  __shared__ __align__(16) uint_t sPT[4][512];   // per-wave 2 KB P^T scratch

  const int tid = threadIdx.x;
  const int lane = tid & 63, w = tid >> 6;
  const int col = lane & 15, quad = lane >> 4;

  // staging sources (fragment-mapped): wave w stages blocks w and 4+w.
  const ushort_t* kbase = Kp + (size_t)(w * 16 + col) * HD + quad * 8;
  const ushort_t* vbase = Vt + (size_t)(w * 16 + col) * S + quad * 8;

  bf16x8 qf[2][2];
#pragma unroll
  for (int s = 0; s < 2; ++s) {
    const ushort_t* qp = Qp + (size_t)(qt * 128 + s * 64 + w * 16 + col) * HD;
    qf[s][0] = *(const bf16x8*)(qp + quad * 8);
    qf[s][1] = *(const bf16x8*)(qp + 32 + quad * 8);
  }

  float m_i[2] = {-1e30f, -1e30f};
  f32x4 l_acc[2] = {};
  f32x4 o[2][4] = {};
  uint_t* myPT = sPT[w];
  // P^T scratch mapping (verified bijection):
  //   src lane (col,q) word (nt,ws) -> dword wb + nt*128 + ws,
  //   wb = (q>>1)*64 + col*4 + (q&1)*2; read: b128 at f*256 + lane*4.
  const int wb = (quad >> 1) * 64 + col * 4 + (quad & 1) * 2;
  const int rdo = lane * 4;

  bf16x8 onesf;  // 8 x bf16(1.0) for the row-sum MFMA
  {
    union { uint_t u[4]; bf16x8 v; } ou;
    ou.u[0] = ou.u[1] = ou.u[2] = ou.u[3] = 0x3F803F80u;
    onesf = ou.v;
  }

  uint4 kr0, kr1, vr0, vr1;
  {
    const ushort_t* ks = kbase + (size_t)jstart * 64 * HD;
    kr0 = *(const uint4*)ks; kr1 = *(const uint4*)(ks + 32);
    const ushort_t* vs = vbase + jstart * 64;
    vr0 = *(const uint4*)vs; vr1 = *(const uint4*)(vs + 32);
  }

  for (int jt = jstart; jt <= jend; ++jt) {
    __syncthreads();
    *(uint4*)&sK[tid * 8] = kr0;  *(uint4*)&sK[2048 + tid * 8] = kr1;
    *(uint4*)&sV[tid * 8] = vr0;  *(uint4*)&sV[2048 + tid * 8] = vr1;
    __syncthreads();
    if (jt < jend) {
      const ushort_t* ks = kbase + (size_t)(jt + 1) * 64 * HD;
      kr0 = *(const uint4*)ks; kr1 = *(const uint4*)(ks + 32);
      const ushort_t* vs = vbase + (jt + 1) * 64;
      vr0 = *(const uint4*)vs; vr1 = *(const uint4*)(vs + 32);
    }

    f32x4 sc[2][4];
    __builtin_amdgcn_s_setprio(1);
#pragma unroll
    for (int nt = 0; nt < 4; ++nt) {
      bf16x8 kf0 = *(const bf16x8*)&sK[(nt * 64 + lane) * 8];
      bf16x8 kf1 = *(const bf16x8*)&sK[((4 + nt) * 64 + lane) * 8];
      f32x4 z = {0.f, 0.f, 0.f, 0.f};
      z = __builtin_amdgcn_mfma_f32_16x16x32_bf16(kf0, qf[0][0], z, 0, 0, 0);
      z = __builtin_amdgcn_mfma_f32_16x16x32_bf16(kf1, qf[0][1], z, 0, 0, 0);
      sc[0][nt] = z;
      f32x4 y = {0.f, 0.f, 0.f, 0.f};
      y = __builtin_amdgcn_mfma_f32_16x16x32_bf16(kf0, qf[1][0], y, 0, 0, 0);
      y = __builtin_amdgcn_mfma_f32_16x16x32_bf16(kf1, qf[1][1], y, 0, 0, 0);
      sc[1][nt] = y;
    }
    __builtin_amdgcn_s_setprio(0);

    const bool mask0 = (jt >= 2 * qt);
    const bool mask1 = (jt == 2 * qt + 1);
    bf16x8 ptf[2][2];

    auto softmax_strip = [&](int s, bool maskf) {
      const int qrow = qt * 128 + s * 64 + w * 16 + col;
      float p[4][4];
#pragma unroll
      for (int nt = 0; nt < 4; ++nt)
#pragma unroll
        for (int r = 0; r < 4; ++r) p[nt][r] = sc[s][nt][r];
      if (maskf) {
#pragma unroll
        for (int nt = 0; nt < 4; ++nt)
#pragma unroll
          for (int r = 0; r < 4; ++r)
            if (jt * 64 + nt * 16 + quad * 4 + r > qrow) p[nt][r] = -1e30f;
      }
      // tree max
      float mx[4];
#pragma unroll
      for (int nt = 0; nt < 4; ++nt)
        mx[nt] = fmaxf(fmaxf(p[nt][0], p[nt][1]), fmaxf(p[nt][2], p[nt][3]));
      float t = fmaxf(fmaxf(mx[0], mx[1]), fmaxf(mx[2], mx[3]));
      t = fmaxf(t, __shfl_xor(t, 16));
      t = fmaxf(t, __shfl_xor(t, 32));
      float mnew = m_i[s];
      if (__ballot(t > m_i[s])) {  // wave-uniform: some lane must rescale
        mnew = fmaxf(m_i[s], t);
        float alpha = __builtin_amdgcn_exp2f(m_i[s] - mnew);
        m_i[s] = mnew;
        l_acc[s] *= alpha;
#pragma unroll
        for (int dt = 0; dt < 4; ++dt) o[s][dt] *= alpha;
      }
#pragma unroll
      for (int nt = 0; nt < 4; ++nt) {
#pragma unroll
        for (int r = 0; r < 4; ++r)
          p[nt][r] = __builtin_amdgcn_exp2f(p[nt][r] - mnew);
        uint2 dd;
        dd.x = pack2bf(p[nt][0], p[nt][1]);
        dd.y = pack2bf(p[nt][2], p[nt][3]);
        *(uint2*)&myPT[wb + nt * 128] = dd;
      }
      ptf[s][0] = *(const bf16x8*)&myPT[rdo];
      ptf[s][1] = *(const bf16x8*)&myPT[256 + rdo];
    };
    softmax_strip(0, mask0);
    softmax_strip(1, mask1);

    __builtin_amdgcn_s_setprio(1);
#pragma unroll
    for (int dt = 0; dt < 4; ++dt) {
      bf16x8 vf0 = *(const bf16x8*)&sV[(dt * 64 + lane) * 8];
      bf16x8 vf1 = *(const bf16x8*)&sV[((4 + dt) * 64 + lane) * 8];
      o[0][dt] = __builtin_amdgcn_mfma_f32_16x16x32_bf16(vf0, ptf[0][0], o[0][dt], 0, 0, 0);
      o[0][dt] = __builtin_amdgcn_mfma_f32_16x16x32_bf16(vf1, ptf[0][1], o[0][dt], 0, 0, 0);
      o[1][dt] = __builtin_amdgcn_mfma_f32_16x16x32_bf16(vf0, ptf[1][0], o[1][dt], 0, 0, 0);
      o[1][dt] = __builtin_amdgcn_mfma_f32_16x16x32_bf16(vf1, ptf[1][1], o[1][dt], 0, 0, 0);
    }
    // row-sum of P via ones-row MFMA (all accumulator rows identical per col)
    l_acc[0] = __builtin_amdgcn_mfma_f32_16x16x32_bf16(onesf, ptf[0][0], l_acc[0], 0, 0, 0);
    l_acc[0] = __builtin_amdgcn_mfma_f32_16x16x32_bf16(onesf, ptf[0][1], l_acc[0], 0, 0, 0);
    l_acc[1] = __builtin_amdgcn_mfma_f32_16x16x32_bf16(onesf, ptf[1][0], l_acc[1], 0, 0, 0);
    l_acc[1] = __builtin_amdgcn_mfma_f32_16x16x32_bf16(onesf, ptf[1][1], l_acc[1], 0, 0, 0);
    __builtin_amdgcn_s_setprio(0);
  }

#pragma unroll
  for (int s = 0; s < 2; ++s) {
    const float lv = l_acc[s][0];
    if (direct) {
      const float inv = 1.0f / lv;
      const int q = qt * 128 + s * 64 + w * 16 + col;
      ushort_t* base = ctx + ((size_t)(b * S + q)) * 768 + h * 64;
#pragma unroll
      for (int dt = 0; dt < 4; ++dt) {
        uint2 dd;
        dd.x = pack2bf(o[s][dt][0] * inv, o[s][dt][1] * inv);
        dd.y = pack2bf(o[s][dt][2] * inv, o[s][dt][3] * inv);
        *(uint2*)(base + dt * 16 + quad * 4) = dd;
      }
    } else {
      const int row = s * 64 + w * 16 + col;
      ushort_t* base = (slot < 768 ? op0 + (size_t)slot * 8192
                                   : op1 + (size_t)(slot - 768) * 8192) + row * 64;
#pragma unroll
      for (int dt = 0; dt < 4; ++dt) {
        uint2 dd;
        dd.x = pack2bf(o[s][dt][0], o[s][dt][1]);
        dd.y = pack2bf(o[s][dt][2], o[s][dt][3]);
        *(uint2*)(base + dt * 16 + quad * 4) = dd;
      }
      if (lane < 16) {
        m_part[slot * 128 + s * 64 + w * 16 + lane] = m_i[s];
        l_part[slot * 128 + s * 64 + w * 16 + lane] = lv;
      }
    }
  }
}

// ---------------------------------------------------------------------------
// Merge the C(qt) partials for qt >= 6 (128 rows per qt).  Grid: (26, 24).
// ---------------------------------------------------------------------------
__global__ __launch_bounds__(256) void flash_merge(const ushort_t* __restrict__ op0,
                                                   const ushort_t* __restrict__ op1,
                                                   const float* __restrict__ m_part,
                                                   const float* __restrict__ l_part,
                                                   ushort_t* __restrict__ ctx) {
  const int qt = 6 + blockIdx.x;            // 6..31
  const int bh = blockIdx.y;
  const int b = bh / 12, h = bh - b * 12;
  const int C = (qt + 6) / 6;
  int sb = 0;
  for (int q = 6; q < qt; ++q) sb += (q + 6) / 6;
  const int slot0 = bh * 96 + sb;
  const int t = threadIdx.x;
  const int q = t >> 1, dc = (t & 1) * 32;
  float m_g = -1e30f;
  for (int cc = 0; cc < C; ++cc)
    m_g = fmaxf(m_g, m_part[(slot0 + cc) * 128 + q]);
  float lsum = 0.f;
  float acc[32] = {};
  for (int cc = 0; cc < C; ++cc) {
    const int sl = slot0 + cc;
    const float wgt = __builtin_amdgcn_exp2f(m_part[sl * 128 + q] - m_g);
    lsum += wgt * l_part[sl * 128 + q];
    const ushort_t* p = (sl < 768 ? op0 + (size_t)sl * 8192
                                  : op1 + (size_t)(sl - 768) * 8192) + q * 64 + dc;
    ushort_t a[32];
#pragma unroll
    for (int k = 0; k < 32; k += 8) *(uint4*)&a[k] = *(const uint4*)(p + k);
#pragma unroll
    for (int k = 0; k < 32; ++k) acc[k] += wgt * bf2f(a[k]);
  }
  const float inv = 1.0f / lsum;
  ushort_t outv[32];
#pragma unroll
  for (int k = 0; k < 32; ++k) outv[k] = f2bf(acc[k] * inv);
  ushort_t* dst = ctx + ((size_t)(b * 4096 + qt * 128 + q)) * 768 + h * 64 + dc;
#pragma unroll
  for (int k = 0; k < 32; k += 8) *(uint4*)(dst + k) = *(const uint4*)&outv[k];
}

// ---------------------------------------------------------------------------
extern "C" void kernel_launch(void* const* d_in, const int* in_sizes, int n_in,
                              void* d_out, int out_size, void* d_ws, size_t ws_size,
                              hipStream_t stream) {
  (void)in_sizes; (void)n_in; (void)out_size; (void)ws_size;
  const float* x = (const float*)d_in[0];       // [2][4096][768] fp32
  const float* w_qkv = (const float*)d_in[1];   // [768][2304] fp32
  const float* w_out = (const float*)d_in[2];   // [768][768] fp32
  float* out = (float*)d_out;                   // [2][4096][768] fp32

  ushort_t* ws = (ushort_t*)d_ws;
  ushort_t* wqkv_t = ws;                                 // 2304*768 bf16
  ushort_t* wout_t = wqkv_t + 2304 * 768;                // 768*768 bf16
  ushort_t* qkv = wout_t + 768 * 768;                    // 3*24*4096*64 bf16
  ushort_t* v_t = qkv + 3 * 24 * 4096 * 64;              // 24*64*4096 bf16
  ushort_t* ctx = v_t + 24 * 64 * 4096;                  // 8192*768 bf16
  ushort_t* x_bf = ctx + 8192 * 768;                     // 8192*768 bf16
  // aliases (dead by the time flash runs):
  ushort_t* o_part0 = x_bf;                              // slots 0..767   (12.58 MB)
  ushort_t* o_part1 = (ushort_t*)d_out;                  // slots 768..2303 (25.17 MB,
                                                         //  dead until gemm128_out)
  float* m_part = (float*)wqkv_t;                        // 2304*128 f32
  float* l_part = m_part + 2304 * 128;                   // 2304*128 f32
  // total ws: 80.2 MB (unchanged)

  prep_kernel<<<dim3(3648), 256, 0, stream>>>(x, w_qkv, w_out, x_bf, wqkv_t, wout_t);
  gemm128_qkv<<<dim3(1152), 256, 0, stream>>>(x_bf, wqkv_t, qkv);
  transpose_v<<<dim3(64, 24), 256, 0, stream>>>(qkv + (size_t)48 * 4096 * 64, v_t);
  flash_kernel<<<dim3(102, 24), 256, 0, stream>>>(qkv, v_t, ctx, o_part0, o_part1,
                                                  m_part, l_part);
  flash_merge<<<dim3(26, 24), 256, 0, stream>>>(o_part0, o_part1, m_part, l_part, ctx);
  gemm128_out<<<dim3(64, 6), 256, 0, stream>>>(ctx, wout_t, out);
}

// Round 4
// 262.041 us; speedup vs baseline: 1.0580x; 1.0580x over previous
//
#include <hip/hip_runtime.h>

typedef unsigned short ushort_t;
typedef unsigned int uint_t;
typedef __bf16 bf16x8 __attribute__((ext_vector_type(8)));
typedef float f32x4 __attribute__((ext_vector_type(4)));

__device__ __forceinline__ ushort_t f2bf(float f) {
  union { float f; unsigned u; } x;
  x.f = f;
  unsigned r = x.u + 0x7fffu + ((x.u >> 16) & 1u);
  return (ushort_t)(r >> 16);
}
__device__ __forceinline__ float bf2f(ushort_t u) {
  union { unsigned u; float f; } x;
  x.u = (unsigned)u << 16;
  return x.f;
}
#if __has_builtin(__builtin_amdgcn_cvt_pk_bf16_f32)
__device__ __forceinline__ uint_t pack2bf(float a, float b) {
  auto v = __builtin_amdgcn_cvt_pk_bf16_f32(a, b);
  uint_t u; __builtin_memcpy(&u, &v, 4); return u;
}
#else
__device__ __forceinline__ uint_t pack2bf(float a, float b) {
  return (uint_t)f2bf(a) | ((uint_t)f2bf(b) << 16);
}
#endif

// async global->LDS, 16 B/lane; LDS dest = wave-uniform base + lane*16.
__device__ __forceinline__ void async_copy16(const ushort_t* g, ushort_t* l) {
  __builtin_amdgcn_global_load_lds(
      (const __attribute__((address_space(1))) unsigned int*)g,
      (__attribute__((address_space(3))) unsigned int*)l, 16, 0, 0);
}

// ---------------------------------------------------------------------------
// Fused prep: [0,3072) convert x fp32->bf16; [3072,3504) transpose w_qkv;
// [3504,3648) transpose w_out.  Grid: (3648), 256 threads.
// ---------------------------------------------------------------------------
__global__ __launch_bounds__(256) void prep_kernel(const float* __restrict__ x,
                                                   const float* __restrict__ w_qkv,
                                                   const float* __restrict__ w_out,
                                                   ushort_t* __restrict__ x_bf,
                                                   ushort_t* __restrict__ wqkv_t,
                                                   ushort_t* __restrict__ wout_t) {
  const int bx = blockIdx.x;
  if (bx < 3072) {  // convert x: 8 elems/thread
    const int i = (bx * 256 + threadIdx.x) * 8;
    float4 a = *(const float4*)(x + i);
    float4 b = *(const float4*)(x + i + 4);
    uint_t t[4];
    t[0] = pack2bf(a.x, a.y); t[1] = pack2bf(a.z, a.w);
    t[2] = pack2bf(b.x, b.y); t[3] = pack2bf(b.z, b.w);
    *(uint4*)(x_bf + i) = *(const uint4*)t;
    return;
  }
  // weight transpose: out[n][k] = bf16(in[k][n]), 64x64 tiles
  const float* in; ushort_t* outp; int K, N, n0, k0;
  if (bx < 3504) {
    int t = bx - 3072;                       // 36 x 12
    in = w_qkv; outp = wqkv_t; K = 768; N = 2304;
    n0 = (t % 36) * 64; k0 = (t / 36) * 64;
  } else {
    int t = bx - 3504;                       // 12 x 12
    in = w_out; outp = wout_t; K = 768; N = 768;
    n0 = (t % 12) * 64; k0 = (t / 12) * 64;
  }
  __shared__ ushort_t s[64][72];
  const int r = threadIdx.x >> 2;
  const int c = (threadIdx.x & 3) * 16;
  const float* src = in + (size_t)(k0 + r) * N + n0 + c;
  float buf[16];
#pragma unroll
  for (int i = 0; i < 16; i += 4) *(float4*)&buf[i] = *(const float4*)(src + i);
  ushort_t t16[16];
#pragma unroll
  for (int i = 0; i < 16; ++i) t16[i] = f2bf(buf[i]);
  *(uint4*)&s[r][c] = *(const uint4*)&t16[0];
  *(uint4*)&s[r][c + 8] = *(const uint4*)&t16[8];
  __syncthreads();
  ushort_t tmp[16];
#pragma unroll
  for (int i = 0; i < 16; ++i) tmp[i] = s[c + i][r];
  ushort_t* dst = outp + (size_t)(n0 + r) * K + k0 + c;
  *(uint4*)&dst[0] = *(const uint4*)&tmp[0];
  *(uint4*)&dst[8] = *(const uint4*)&tmp[8];
}

// ---------------------------------------------------------------------------
// Per-head V transpose: v_t[bh][d][s] = v[bh][s][d].  Grid: (64, 24).
// ---------------------------------------------------------------------------
__global__ __launch_bounds__(256) void transpose_v(const ushort_t* __restrict__ v,
                                                   ushort_t* __restrict__ v_t) {
  __shared__ ushort_t s[64][72];
  const int s0 = blockIdx.x * 64;
  const int bh = blockIdx.y;
  const ushort_t* src = v + ((size_t)bh * 4096 + s0) * 64;
  ushort_t* dst = v_t + (size_t)bh * 64 * 4096 + s0;
  const int r = threadIdx.x >> 2;
  const int c = (threadIdx.x & 3) * 16;
  *(uint4*)&s[r][c] = *(const uint4*)(src + (size_t)r * 64 + c);
  *(uint4*)&s[r][c + 8] = *(const uint4*)(src + (size_t)r * 64 + c + 8);
  __syncthreads();
  ushort_t tmp[16];
#pragma unroll
  for (int i = 0; i < 16; ++i) tmp[i] = s[c + i][r];
  *(uint4*)&dst[(size_t)r * 4096 + c] = *(const uint4*)&tmp[0];
  *(uint4*)&dst[(size_t)r * 4096 + c + 8] = *(const uint4*)&tmp[8];
}

// ---------------------------------------------------------------------------
// GEMM1 (m97-style): qkv = x_bf @ w_qkv.  128x128 tile, BK=32,
// global_load_lds staging.  Q pre-scaled by SCL.  Grid: (1152), 256 threads.
// ---------------------------------------------------------------------------
__global__ __launch_bounds__(256) void gemm128_qkv(const ushort_t* __restrict__ A,
                                                   const ushort_t* __restrict__ Bt,
                                                   ushort_t* __restrict__ qkv) {
  constexpr int K = 768;
  constexpr float SCL = 0.1803368801111137f;  // (1/sqrt(64)) * log2(e)
  __shared__ ushort_t sA[128 * 32];
  __shared__ ushort_t sB[128 * 32];
  const int bid = blockIdx.x;
  const int g = bid / 144, rr = bid - g * 144;
  const int mi = g * 8 + (rr & 7), ni = rr >> 3;   // mi 0..63, ni 0..17
  const int tid = threadIdx.x;
  const int lane = tid & 63, w = tid >> 6;
  const int wm = w >> 1, wn = w & 1;
  const int col = lane & 15, quad = lane >> 4;
  const int m0 = mi * 128, n0 = ni * 128;
  const int row = tid >> 2;
  const int kc = (tid & 3) * 8;
  f32x4 acc[4][4] = {};
  const ushort_t* aptr = A + (size_t)(m0 + row) * K + kc;
  const ushort_t* bptr = Bt + (size_t)(n0 + row) * K + kc;
  ushort_t* lA = sA + w * 512;
  ushort_t* lB = sB + w * 512;
  for (int k0 = 0; k0 < K; k0 += 32) {
    async_copy16(aptr + k0, lA);
    async_copy16(aptr + (size_t)64 * K + k0, lA + 2048);
    async_copy16(bptr + k0, lB);
    async_copy16(bptr + (size_t)64 * K + k0, lB + 2048);
    __syncthreads();
    bf16x8 af[4], bfr[4];
#pragma unroll
    for (int mt = 0; mt < 4; ++mt)
      af[mt] = *(const bf16x8*)&sA[(wm * 64 + mt * 16 + col) * 32 + quad * 8];
#pragma unroll
    for (int nt = 0; nt < 4; ++nt)
      bfr[nt] = *(const bf16x8*)&sB[(wn * 64 + nt * 16 + col) * 32 + quad * 8];
#pragma unroll
    for (int mt = 0; mt < 4; ++mt)
#pragma unroll
      for (int nt = 0; nt < 4; ++nt)
        acc[mt][nt] = __builtin_amdgcn_mfma_f32_16x16x32_bf16(af[mt], bfr[nt],
                                                              acc[mt][nt], 0, 0, 0);
    __syncthreads();
  }
  const int which = ni / 6;                     // 0=Q 1=K 2=V (block-uniform)
  const float qs = (which == 0) ? SCL : 1.0f;
#pragma unroll
  for (int mt = 0; mt < 4; ++mt)
#pragma unroll
    for (int nt = 0; nt < 4; ++nt)
#pragma unroll
      for (int r = 0; r < 4; ++r) {
        int m = m0 + wm * 64 + mt * 16 + quad * 4 + r;
        int n = n0 + wn * 64 + nt * 16 + col;
        int rem = n - which * 768;
        int h = rem >> 6, d = rem & 63;
        int b = m >> 12, s = m & 4095;
        qkv[(((size_t)(which * 24 + b * 12 + h) * 4096 + s) << 6) + d] =
            f2bf(acc[mt][nt][r] * qs);
      }
}

// ---------------------------------------------------------------------------
// GEMM2 (m97-style): out = ctx @ w_out, fp32 out.  Grid: (64, 6).
// ---------------------------------------------------------------------------
__global__ __launch_bounds__(256) void gemm128_out(const ushort_t* __restrict__ A,
                                                   const ushort_t* __restrict__ Bt,
                                                   float* __restrict__ out) {
  constexpr int K = 768;
  __shared__ ushort_t sA[128 * 32];
  __shared__ ushort_t sB[128 * 32];
  const int tid = threadIdx.x;
  const int lane = tid & 63, w = tid >> 6;
  const int wm = w >> 1, wn = w & 1;
  const int col = lane & 15, quad = lane >> 4;
  const int m0 = blockIdx.x * 128, n0 = blockIdx.y * 128;
  const int row = tid >> 2;
  const int kc = (tid & 3) * 8;
  f32x4 acc[4][4] = {};
  const ushort_t* aptr = A + (size_t)(m0 + row) * K + kc;
  const ushort_t* bptr = Bt + (size_t)(n0 + row) * K + kc;
  ushort_t* lA = sA + w * 512;
  ushort_t* lB = sB + w * 512;
  for (int k0 = 0; k0 < K; k0 += 32) {
    async_copy16(aptr + k0, lA);
    async_copy16(aptr + (size_t)64 * K + k0, lA + 2048);
    async_copy16(bptr + k0, lB);
    async_copy16(bptr + (size_t)64 * K + k0, lB + 2048);
    __syncthreads();
    bf16x8 af[4], bfr[4];
#pragma unroll
    for (int mt = 0; mt < 4; ++mt)
      af[mt] = *(const bf16x8*)&sA[(wm * 64 + mt * 16 + col) * 32 + quad * 8];
#pragma unroll
    for (int nt = 0; nt < 4; ++nt)
      bfr[nt] = *(const bf16x8*)&sB[(wn * 64 + nt * 16 + col) * 32 + quad * 8];
#pragma unroll
    for (int mt = 0; mt < 4; ++mt)
#pragma unroll
      for (int nt = 0; nt < 4; ++nt)
        acc[mt][nt] = __builtin_amdgcn_mfma_f32_16x16x32_bf16(af[mt], bfr[nt],
                                                              acc[mt][nt], 0, 0, 0);
    __syncthreads();
  }
#pragma unroll
  for (int mt = 0; mt < 4; ++mt)
#pragma unroll
    for (int nt = 0; nt < 4; ++nt)
#pragma unroll
      for (int r = 0; r < 4; ++r) {
        int m = m0 + wm * 64 + mt * 16 + quad * 4 + r;
        int n = n0 + wn * 64 + nt * 16 + col;
        out[(size_t)m * 768 + n] = acc[mt][nt][r];
      }
}

// ---------------------------------------------------------------------------
// Flash attention, causal, S^T formulation, Q-tile 128, UNIFORM SPLIT-K.
// Round-4: fragment-linear conflict-free LDS (kept from r3) + shuffle
// row-sum (reverted from r3's ones-MFMA l_acc: the extra 12 accumulator
// regs pushed the 128-reg/wave envelope over -> scratch spills, WRITE_SIZE
// 41->76 MB, +10us.  Register budget here is exactly at the 4-wave/EU
// cliff; do not add accumulator state).
// LDS 24 KB.  launch_bounds(256,4): do NOT raise (r1: ,5 capped VGPR at
// 48 -> spills).
// ---------------------------------------------------------------------------
__global__ __launch_bounds__(256, 4) void flash_kernel(const ushort_t* __restrict__ qkv,
                                                       const ushort_t* __restrict__ v_t,
                                                       ushort_t* __restrict__ ctx,
                                                       ushort_t* __restrict__ op0,
                                                       ushort_t* __restrict__ op1,
                                                       float* __restrict__ m_part,
                                                       float* __restrict__ l_part) {
  constexpr int S = 4096;
  constexpr int HD = 64;
  const int bh = blockIdx.y;
  const int b = bh / 12, h = bh - b * 12;

  // blockIdx.x -> (qt, chunk c), heavy qt first (bx=0 -> qt=31,c=0).
  int rem = blockIdx.x, qt = 31, C;
  for (;;) {
    C = (qt + 6) / 6;
    if (rem < C) break;
    rem -= C; --qt;
  }
  const int c = rem;
  const int T = 2 * qt + 2;                 // total KV tiles for this qt
  const bool direct = (C == 1);
  const int jstart = (c * T) / C;
  const int jend = ((c + 1) * T) / C - 1;   // inclusive
  int sb = 0;                               // partial-slot base for this qt
  for (int q = 6; q < qt; ++q) sb += (q + 6) / 6;
  const int slot = bh * 96 + sb + c;

  const ushort_t* Qp = qkv + (size_t)bh * S * HD;
  const ushort_t* Kp = qkv + (size_t)(24 + bh) * S * HD;
  const ushort_t* Vt = v_t + (size_t)bh * HD * S;

  // Fragment-linear LDS: 8 blocks x (64 lanes x 16B) each for K and V.
  __shared__ __align__(16) ushort_t sK[4096];
  __shared__ __align__(16) ushort_t sV[4096];
  __shared__ __align__(16) uint_t sPT[4][512];   // per-wave 2 KB P^T scratch

  const int tid = threadIdx.x;
  const int lane = tid & 63, w = tid >> 6;
  const int col = lane & 15, quad = lane >> 4;

  // staging sources (fragment-mapped): wave w stages blocks w and 4+w.
  const ushort_t* kbase = Kp + (size_t)(w * 16 + col) * HD + quad * 8;
  const ushort_t* vbase = Vt + (size_t)(w * 16 + col) * S + quad * 8;

  bf16x8 qf[2][2];
#pragma unroll
  for (int s = 0; s < 2; ++s) {
    const ushort_t* qp = Qp + (size_t)(qt * 128 + s * 64 + w * 16 + col) * HD;
    qf[s][0] = *(const bf16x8*)(qp + quad * 8);
    qf[s][1] = *(const bf16x8*)(qp + 32 + quad * 8);
  }

  float m_i[2] = {-1e30f, -1e30f}, l_i[2] = {0.f, 0.f};
  f32x4 o[2][4] = {};
  uint_t* myPT = sPT[w];
  // P^T scratch mapping (verified bijection):
  //   src lane (col,q) word (nt,ws) -> dword wb + nt*128 + ws,
  //   wb = (q>>1)*64 + col*4 + (q&1)*2; read: b128 at f*256 + lane*4.
  const int wb = (quad >> 1) * 64 + col * 4 + (quad & 1) * 2;
  const int rdo = lane * 4;

  uint4 kr0, kr1, vr0, vr1;
  {
    const ushort_t* ks = kbase + (size_t)jstart * 64 * HD;
    kr0 = *(const uint4*)ks; kr1 = *(const uint4*)(ks + 32);
    const ushort_t* vs = vbase + jstart * 64;
    vr0 = *(const uint4*)vs; vr1 = *(const uint4*)(vs + 32);
  }

  for (int jt = jstart; jt <= jend; ++jt) {
    __syncthreads();
    *(uint4*)&sK[tid * 8] = kr0;  *(uint4*)&sK[2048 + tid * 8] = kr1;
    *(uint4*)&sV[tid * 8] = vr0;  *(uint4*)&sV[2048 + tid * 8] = vr1;
    __syncthreads();
    if (jt < jend) {
      const ushort_t* ks = kbase + (size_t)(jt + 1) * 64 * HD;
      kr0 = *(const uint4*)ks; kr1 = *(const uint4*)(ks + 32);
      const ushort_t* vs = vbase + (jt + 1) * 64;
      vr0 = *(const uint4*)vs; vr1 = *(const uint4*)(vs + 32);
    }

    f32x4 sc[2][4];
    __builtin_amdgcn_s_setprio(1);
#pragma unroll
    for (int nt = 0; nt < 4; ++nt) {
      bf16x8 kf0 = *(const bf16x8*)&sK[(nt * 64 + lane) * 8];
      bf16x8 kf1 = *(const bf16x8*)&sK[((4 + nt) * 64 + lane) * 8];
      f32x4 z = {0.f, 0.f, 0.f, 0.f};
      z = __builtin_amdgcn_mfma_f32_16x16x32_bf16(kf0, qf[0][0], z, 0, 0, 0);
      z = __builtin_amdgcn_mfma_f32_16x16x32_bf16(kf1, qf[0][1], z, 0, 0, 0);
      sc[0][nt] = z;
      f32x4 y = {0.f, 0.f, 0.f, 0.f};
      y = __builtin_amdgcn_mfma_f32_16x16x32_bf16(kf0, qf[1][0], y, 0, 0, 0);
      y = __builtin_amdgcn_mfma_f32_16x16x32_bf16(kf1, qf[1][1], y, 0, 0, 0);
      sc[1][nt] = y;
    }
    __builtin_amdgcn_s_setprio(0);

    const bool mask0 = (jt >= 2 * qt);
    const bool mask1 = (jt == 2 * qt + 1);
    bf16x8 ptf[2][2];

    auto softmax_strip = [&](int s, bool maskf) {
      const int qrow = qt * 128 + s * 64 + w * 16 + col;
      float p[4][4];
#pragma unroll
      for (int nt = 0; nt < 4; ++nt)
#pragma unroll
        for (int r = 0; r < 4; ++r) p[nt][r] = sc[s][nt][r];
      if (maskf) {
#pragma unroll
        for (int nt = 0; nt < 4; ++nt)
#pragma unroll
          for (int r = 0; r < 4; ++r)
            if (jt * 64 + nt * 16 + quad * 4 + r > qrow) p[nt][r] = -1e30f;
      }
      // tree max
      float mx[4];
#pragma unroll
      for (int nt = 0; nt < 4; ++nt)
        mx[nt] = fmaxf(fmaxf(p[nt][0], p[nt][1]), fmaxf(p[nt][2], p[nt][3]));
      float t = fmaxf(fmaxf(mx[0], mx[1]), fmaxf(mx[2], mx[3]));
      t = fmaxf(t, __shfl_xor(t, 16));
      t = fmaxf(t, __shfl_xor(t, 32));
      float mnew = m_i[s];
      if (__ballot(t > m_i[s])) {  // wave-uniform: some lane must rescale
        mnew = fmaxf(m_i[s], t);
        float alpha = __builtin_amdgcn_exp2f(m_i[s] - mnew);
        m_i[s] = mnew;
        l_i[s] *= alpha;
#pragma unroll
        for (int dt = 0; dt < 4; ++dt) o[s][dt] *= alpha;
      }
      float rsn[4];
#pragma unroll
      for (int nt = 0; nt < 4; ++nt) {
#pragma unroll
        for (int r = 0; r < 4; ++r)
          p[nt][r] = __builtin_amdgcn_exp2f(p[nt][r] - mnew);
        rsn[nt] = (p[nt][0] + p[nt][1]) + (p[nt][2] + p[nt][3]);
      }
      float rs = (rsn[0] + rsn[1]) + (rsn[2] + rsn[3]);
      rs += __shfl_xor(rs, 16);
      rs += __shfl_xor(rs, 32);
      l_i[s] += rs;
#pragma unroll
      for (int nt = 0; nt < 4; ++nt) {
        uint2 dd;
        dd.x = pack2bf(p[nt][0], p[nt][1]);
        dd.y = pack2bf(p[nt][2], p[nt][3]);
        *(uint2*)&myPT[wb + nt * 128] = dd;
      }
      ptf[s][0] = *(const bf16x8*)&myPT[rdo];
      ptf[s][1] = *(const bf16x8*)&myPT[256 + rdo];
    };
    softmax_strip(0, mask0);
    softmax_strip(1, mask1);

    __builtin_amdgcn_s_setprio(1);
#pragma unroll
    for (int dt = 0; dt < 4; ++dt) {
      bf16x8 vf0 = *(const bf16x8*)&sV[(dt * 64 + lane) * 8];
      bf16x8 vf1 = *(const bf16x8*)&sV[((4 + dt) * 64 + lane) * 8];
      o[0][dt] = __builtin_amdgcn_mfma_f32_16x16x32_bf16(vf0, ptf[0][0], o[0][dt], 0, 0, 0);
      o[0][dt] = __builtin_amdgcn_mfma_f32_16x16x32_bf16(vf1, ptf[0][1], o[0][dt], 0, 0, 0);
      o[1][dt] = __builtin_amdgcn_mfma_f32_16x16x32_bf16(vf0, ptf[1][0], o[1][dt], 0, 0, 0);
      o[1][dt] = __builtin_amdgcn_mfma_f32_16x16x32_bf16(vf1, ptf[1][1], o[1][dt], 0, 0, 0);
    }
    __builtin_amdgcn_s_setprio(0);
  }

#pragma unroll
  for (int s = 0; s < 2; ++s) {
    if (direct) {
      const float inv = 1.0f / l_i[s];
      const int q = qt * 128 + s * 64 + w * 16 + col;
      ushort_t* base = ctx + ((size_t)(b * S + q)) * 768 + h * 64;
#pragma unroll
      for (int dt = 0; dt < 4; ++dt) {
        uint2 dd;
        dd.x = pack2bf(o[s][dt][0] * inv, o[s][dt][1] * inv);
        dd.y = pack2bf(o[s][dt][2] * inv, o[s][dt][3] * inv);
        *(uint2*)(base + dt * 16 + quad * 4) = dd;
      }
    } else {
      const int row = s * 64 + w * 16 + col;
      ushort_t* base = (slot < 768 ? op0 + (size_t)slot * 8192
                                   : op1 + (size_t)(slot - 768) * 8192) + row * 64;
#pragma unroll
      for (int dt = 0; dt < 4; ++dt) {
        uint2 dd;
        dd.x = pack2bf(o[s][dt][0], o[s][dt][1]);
        dd.y = pack2bf(o[s][dt][2], o[s][dt][3]);
        *(uint2*)(base + dt * 16 + quad * 4) = dd;
      }
      if (lane < 16) {
        m_part[slot * 128 + s * 64 + w * 16 + lane] = m_i[s];
        l_part[slot * 128 + s * 64 + w * 16 + lane] = l_i[s];
      }
    }
  }
}

// ---------------------------------------------------------------------------
// Merge the C(qt) partials for qt >= 6 (128 rows per qt).  Grid: (26, 24).
// ---------------------------------------------------------------------------
__global__ __launch_bounds__(256) void flash_merge(const ushort_t* __restrict__ op0,
                                                   const ushort_t* __restrict__ op1,
                                                   const float* __restrict__ m_part,
                                                   const float* __restrict__ l_part,
                                                   ushort_t* __restrict__ ctx) {
  const int qt = 6 + blockIdx.x;            // 6..31
  const int bh = blockIdx.y;
  const int b = bh / 12, h = bh - b * 12;
  const int C = (qt + 6) / 6;
  int sb = 0;
  for (int q = 6; q < qt; ++q) sb += (q + 6) / 6;
  const int slot0 = bh * 96 + sb;
  const int t = threadIdx.x;
  const int q = t >> 1, dc = (t & 1) * 32;
  float m_g = -1e30f;
  for (int cc = 0; cc < C; ++cc)
    m_g = fmaxf(m_g, m_part[(slot0 + cc) * 128 + q]);
  float lsum = 0.f;
  float acc[32] = {};
  for (int cc = 0; cc < C; ++cc) {
    const int sl = slot0 + cc;
    const float wgt = __builtin_amdgcn_exp2f(m_part[sl * 128 + q] - m_g);
    lsum += wgt * l_part[sl * 128 + q];
    const ushort_t* p = (sl < 768 ? op0 + (size_t)sl * 8192
                                  : op1 + (size_t)(sl - 768) * 8192) + q * 64 + dc;
    ushort_t a[32];
#pragma unroll
    for (int k = 0; k < 32; k += 8) *(uint4*)&a[k] = *(const uint4*)(p + k);
#pragma unroll
    for (int k = 0; k < 32; ++k) acc[k] += wgt * bf2f(a[k]);
  }
  const float inv = 1.0f / lsum;
  ushort_t outv[32];
#pragma unroll
  for (int k = 0; k < 32; ++k) outv[k] = f2bf(acc[k] * inv);
  ushort_t* dst = ctx + ((size_t)(b * 4096 + qt * 128 + q)) * 768 + h * 64 + dc;
#pragma unroll
  for (int k = 0; k < 32; k += 8) *(uint4*)(dst + k) = *(const uint4*)&outv[k];
}

// ---------------------------------------------------------------------------
extern "C" void kernel_launch(void* const* d_in, const int* in_sizes, int n_in,
                              void* d_out, int out_size, void* d_ws, size_t ws_size,
                              hipStream_t stream) {
  (void)in_sizes; (void)n_in; (void)out_size; (void)ws_size;
  const float* x = (const float*)d_in[0];       // [2][4096][768] fp32
  const float* w_qkv = (const float*)d_in[1];   // [768][2304] fp32
  const float* w_out = (const float*)d_in[2];   // [768][768] fp32
  float* out = (float*)d_out;                   // [2][4096][768] fp32

  ushort_t* ws = (ushort_t*)d_ws;
  ushort_t* wqkv_t = ws;                                 // 2304*768 bf16
  ushort_t* wout_t = wqkv_t + 2304 * 768;                // 768*768 bf16
  ushort_t* qkv = wout_t + 768 * 768;                    // 3*24*4096*64 bf16
  ushort_t* v_t = qkv + 3 * 24 * 4096 * 64;              // 24*64*4096 bf16
  ushort_t* ctx = v_t + 24 * 64 * 4096;                  // 8192*768 bf16
  ushort_t* x_bf = ctx + 8192 * 768;                     // 8192*768 bf16
  // aliases (dead by the time flash runs):
  ushort_t* o_part0 = x_bf;                              // slots 0..767   (12.58 MB)
  ushort_t* o_part1 = (ushort_t*)d_out;                  // slots 768..2303 (25.17 MB,
                                                         //  dead until gemm128_out)
  float* m_part = (float*)wqkv_t;                        // 2304*128 f32
  float* l_part = m_part + 2304 * 128;                   // 2304*128 f32
  // total ws: 80.2 MB (unchanged)

  prep_kernel<<<dim3(3648), 256, 0, stream>>>(x, w_qkv, w_out, x_bf, wqkv_t, wout_t);
  gemm128_qkv<<<dim3(1152), 256, 0, stream>>>(x_bf, wqkv_t, qkv);
  transpose_v<<<dim3(64, 24), 256, 0, stream>>>(qkv + (size_t)48 * 4096 * 64, v_t);
  flash_kernel<<<dim3(102, 24), 256, 0, stream>>>(qkv, v_t, ctx, o_part0, o_part1,
                                                  m_part, l_part);
  flash_merge<<<dim3(26, 24), 256, 0, stream>>>(o_part0, o_part1, m_part, l_part, ctx);
  gemm128_out<<<dim3(64, 6), 256, 0, stream>>>(ctx, wout_t, out);
}